// Round 1
// baseline (9398.871 us; speedup 1.0000x reference)
//
#include <hip/hip_runtime.h>
#include <cstddef>

#define HD 512
#define FF 2048
#define VOUT 1024
#define KJOINT 2048

// ---------------------------------------------------------------------------
// Embedding kernels
// ---------------------------------------------------------------------------
__global__ __launch_bounds__(256) void embed_audio_kernel(
    const float* __restrict__ inp,   // [B,80,T]
    const float* __restrict__ w,     // [512,80]
    const float* __restrict__ bias,  // [512]
    const float* __restrict__ pos,   // [P,512]
    float* __restrict__ x, int T) {
  int bt = blockIdx.x;
  int b = bt / T, t = bt - b * T;
  int tid = threadIdx.x;
  __shared__ __align__(16) float col[80];
  if (tid < 80) col[tid] = inp[((size_t)b * 80 + tid) * T + t];
  __syncthreads();
  for (int h = tid; h < HD; h += 256) {
    const float* wr = w + (size_t)h * 80;
    float acc = 0.f;
#pragma unroll
    for (int c = 0; c < 80; c++) acc += col[c] * wr[c];
    x[(size_t)bt * HD + h] = acc + bias[h] + pos[(size_t)t * HD + h];
  }
}

__global__ __launch_bounds__(256) void embed_label_kernel(
    const int* __restrict__ labels,  // [B,U]
    const float* __restrict__ word,  // [V,512]
    const float* __restrict__ pos,   // [P,512]
    float* __restrict__ y, int U) {
  int bu = blockIdx.x;
  int u = bu % U;
  int tid = threadIdx.x;
  int id = labels[bu];
  for (int h = tid; h < HD; h += 256)
    y[(size_t)bu * HD + h] = word[(size_t)id * HD + h] + pos[(size_t)u * HD + h];
}

// ---------------------------------------------------------------------------
// Generic f32 GEMM: C[M,N] = act(A[M,K] @ B[N,K]^T + bias[N])
// 64x64 tile, K-step 16, [k][m] LDS layout, 256 threads, 4x4 per thread.
// Requires M%64==0, N%64==0, K%16==0 (true for all call sites).
// ---------------------------------------------------------------------------
template <int ACT>
__global__ __launch_bounds__(256) void gemm_kernel(
    const float* __restrict__ A, int lda,
    const float* __restrict__ B, int ldb,
    const float* __restrict__ bias,
    float* __restrict__ C, int M, int N, int K) {
  __shared__ __align__(16) float As[16][64];
  __shared__ __align__(16) float Bs[16][64];
  int by = blockIdx.y * 64;  // m
  int bx = blockIdx.x * 64;  // n
  int tid = threadIdx.x;
  int tx = tid & 15, ty = tid >> 4;
  int lm = tid & 63, lkq = (tid >> 6) << 2;
  const float* Ap = A + (size_t)(by + lm) * lda + lkq;
  const float* Bp = B + (size_t)(bx + lm) * ldb + lkq;
  float acc[4][4] = {};
  for (int k0 = 0; k0 < K; k0 += 16) {
    float4 av = *(const float4*)(Ap + k0);
    float4 bv = *(const float4*)(Bp + k0);
    As[lkq + 0][lm] = av.x; As[lkq + 1][lm] = av.y;
    As[lkq + 2][lm] = av.z; As[lkq + 3][lm] = av.w;
    Bs[lkq + 0][lm] = bv.x; Bs[lkq + 1][lm] = bv.y;
    Bs[lkq + 2][lm] = bv.z; Bs[lkq + 3][lm] = bv.w;
    __syncthreads();
#pragma unroll
    for (int k = 0; k < 16; k++) {
      float4 a4 = *(const float4*)&As[k][ty << 2];
      float4 b4 = *(const float4*)&Bs[k][tx << 2];
      float a[4] = {a4.x, a4.y, a4.z, a4.w};
      float b[4] = {b4.x, b4.y, b4.z, b4.w};
#pragma unroll
      for (int i = 0; i < 4; i++)
#pragma unroll
        for (int j = 0; j < 4; j++) acc[i][j] = fmaf(a[i], b[j], acc[i][j]);
    }
    __syncthreads();
  }
  int n0 = bx + (tx << 2);
  float4 bi = bias ? *(const float4*)(bias + n0) : float4{0.f, 0.f, 0.f, 0.f};
#pragma unroll
  for (int i = 0; i < 4; i++) {
    int m = by + (ty << 2) + i;
    float4 v;
    v.x = acc[i][0] + bi.x; v.y = acc[i][1] + bi.y;
    v.z = acc[i][2] + bi.z; v.w = acc[i][3] + bi.w;
    if (ACT == 1) {
      v.x = fmaxf(v.x, 0.f); v.y = fmaxf(v.y, 0.f);
      v.z = fmaxf(v.z, 0.f); v.w = fmaxf(v.w, 0.f);
    }
    *(float4*)(C + (size_t)m * N + n0) = v;
  }
}

// ---------------------------------------------------------------------------
// Attention: one block per (q, head, batch). S <= 256. Mask is all-false.
// qkv layout: [B*S, 1536] with q|k|v thirds, head h at offset h*64.
// ---------------------------------------------------------------------------
__global__ __launch_bounds__(256) void attn_kernel(
    const float* __restrict__ qkv, float* __restrict__ ctx, int S) {
  int q = blockIdx.x, h = blockIdx.y, b = blockIdx.z;
  int tid = threadIdx.x;
  __shared__ __align__(16) float qs[64];
  __shared__ float red[256];
  __shared__ float p[256];
  __shared__ float cred[4][64];
  const float* base = qkv + (size_t)(b * S) * 1536;
  if (tid < 64) qs[tid] = base[(size_t)q * 1536 + h * 64 + tid];
  __syncthreads();
  float score = -1e30f;
  if (tid < S) {
    const float4* k4 = (const float4*)(base + (size_t)tid * 1536 + 512 + h * 64);
    const float4* q4 = (const float4*)qs;
    float acc = 0.f;
#pragma unroll
    for (int d = 0; d < 16; d++) {
      float4 kk = k4[d], qq = q4[d];
      acc += qq.x * kk.x + qq.y * kk.y + qq.z * kk.z + qq.w * kk.w;
    }
    score = acc * 0.125f;
  }
  red[tid] = score;
  __syncthreads();
  for (int s = 128; s > 0; s >>= 1) {
    if (tid < s) red[tid] = fmaxf(red[tid], red[tid + s]);
    __syncthreads();
  }
  float mx = red[0];
  __syncthreads();
  float e = (tid < S) ? __expf(score - mx) : 0.f;
  red[tid] = e;
  __syncthreads();
  for (int s = 128; s > 0; s >>= 1) {
    if (tid < s) red[tid] += red[tid + s];
    __syncthreads();
  }
  float inv = 1.f / red[0];
  p[tid] = e * inv;
  __syncthreads();
  int d = tid & 63, part = tid >> 6;
  float acc = 0.f;
  for (int j = part; j < S; j += 4)
    acc += p[j] * base[(size_t)j * 1536 + 1024 + h * 64 + d];
  cred[part][d] = acc;
  __syncthreads();
  if (tid < 64) {
    float c = cred[0][tid] + cred[1][tid] + cred[2][tid] + cred[3][tid];
    ctx[((size_t)(b * S + q)) * HD + h * 64 + tid] = c;
  }
}

// ---------------------------------------------------------------------------
// Residual add + LayerNorm, in place on x. One block per row, H=512.
// ---------------------------------------------------------------------------
__global__ __launch_bounds__(256) void add_ln_kernel(
    float* __restrict__ x, const float* __restrict__ y,
    const float* __restrict__ s, const float* __restrict__ bsh) {
  int row = blockIdx.x, tid = threadIdx.x;
  float* xr = x + (size_t)row * HD;
  const float* yr = y + (size_t)row * HD;
  float v0 = xr[tid] + yr[tid];
  float v1 = xr[tid + 256] + yr[tid + 256];
  __shared__ float rs_[256], rq_[256];
  rs_[tid] = v0 + v1;
  rq_[tid] = v0 * v0 + v1 * v1;
  __syncthreads();
  for (int st = 128; st > 0; st >>= 1) {
    if (tid < st) { rs_[tid] += rs_[tid + st]; rq_[tid] += rq_[tid + st]; }
    __syncthreads();
  }
  float mean = rs_[0] * (1.f / HD);
  float var = rq_[0] * (1.f / HD) - mean * mean;
  float rstd = rsqrtf(var + 1e-5f);
  xr[tid] = (v0 - mean) * rstd * s[tid] + bsh[tid];
  xr[tid + 256] = (v1 - mean) * rstd * s[tid + 256] + bsh[tid + 256];
}

// ---------------------------------------------------------------------------
// Joint: per block (v_tile=256, t, b). Computes logits[b,t,u,v] (raw, +out_b)
// with on-the-fly h = tanh(ha[b,t,k] + hl[b,u,k]).  U=64, V tile 256, K=2048.
// ---------------------------------------------------------------------------
__global__ __launch_bounds__(256) void joint_kernel(
    const float* __restrict__ ha,  // [B*T, 2048]
    const float* __restrict__ hl,  // [B*U, 2048]
    const float* __restrict__ W,   // [1024, 2048]
    const float* __restrict__ wb,  // [1024]
    float* __restrict__ out, int T, int U) {
  int vt = blockIdx.x * 256, t = blockIdx.y, b = blockIdx.z;
  __shared__ __align__(16) float hs[16][64];
  __shared__ __align__(16) float ws[16][256];
  int tid = threadIdx.x;
  int tu = tid >> 5, tv = tid & 31;  // 8 x 32
  float acc[8][8] = {};
  const float* hab = ha + ((size_t)(b * T + t)) * KJOINT;
  const float* hlb = hl + ((size_t)(b * U)) * KJOINT;
  int lu = tid & 63, lkq = (tid >> 6) << 2;
  const float* wrow = W + (size_t)(vt + tid) * KJOINT;
  for (int k0 = 0; k0 < KJOINT; k0 += 16) {
    float4 hv = *(const float4*)(hlb + (size_t)lu * KJOINT + k0 + lkq);
    float4 av = *(const float4*)(hab + k0 + lkq);
    hs[lkq + 0][lu] = tanhf(av.x + hv.x);
    hs[lkq + 1][lu] = tanhf(av.y + hv.y);
    hs[lkq + 2][lu] = tanhf(av.z + hv.z);
    hs[lkq + 3][lu] = tanhf(av.w + hv.w);
    const float4* w4 = (const float4*)(wrow + k0);
#pragma unroll
    for (int i = 0; i < 4; i++) {
      float4 wv = w4[i];
      ws[i * 4 + 0][tid] = wv.x; ws[i * 4 + 1][tid] = wv.y;
      ws[i * 4 + 2][tid] = wv.z; ws[i * 4 + 3][tid] = wv.w;
    }
    __syncthreads();
#pragma unroll
    for (int k = 0; k < 16; k++) {
      float4 a0 = *(const float4*)&hs[k][tu * 8];
      float4 a1 = *(const float4*)&hs[k][tu * 8 + 4];
      float4 c0 = *(const float4*)&ws[k][tv * 8];
      float4 c1 = *(const float4*)&ws[k][tv * 8 + 4];
      float a[8] = {a0.x, a0.y, a0.z, a0.w, a1.x, a1.y, a1.z, a1.w};
      float c[8] = {c0.x, c0.y, c0.z, c0.w, c1.x, c1.y, c1.z, c1.w};
#pragma unroll
      for (int i = 0; i < 8; i++)
#pragma unroll
        for (int j = 0; j < 8; j++) acc[i][j] = fmaf(a[i], c[j], acc[i][j]);
    }
    __syncthreads();
  }
#pragma unroll
  for (int i = 0; i < 8; i++) {
    int u = tu * 8 + i;
    size_t rowoff = (((size_t)(b * T + t)) * U + u) * VOUT;
#pragma unroll
    for (int j = 0; j < 8; j += 4) {
      int v = vt + tv * 8 + j;
      float4 o;
      o.x = acc[i][j + 0] + wb[v + 0];
      o.y = acc[i][j + 1] + wb[v + 1];
      o.z = acc[i][j + 2] + wb[v + 2];
      o.w = acc[i][j + 3] + wb[v + 3];
      *(float4*)(out + rowoff + v) = o;
    }
  }
}

// ---------------------------------------------------------------------------
// In-place log_softmax over last dim (1024). One block per row.
// ---------------------------------------------------------------------------
__global__ __launch_bounds__(256) void logsoftmax_kernel(float* __restrict__ out) {
  size_t row = blockIdx.x;
  float* p = out + row * VOUT;
  int tid = threadIdx.x;
  float v0 = p[tid], v1 = p[tid + 256], v2 = p[tid + 512], v3 = p[tid + 768];
  __shared__ float red[256];
  float m = fmaxf(fmaxf(v0, v1), fmaxf(v2, v3));
  red[tid] = m;
  __syncthreads();
  for (int s = 128; s > 0; s >>= 1) {
    if (tid < s) red[tid] = fmaxf(red[tid], red[tid + s]);
    __syncthreads();
  }
  float mx = red[0];
  __syncthreads();
  float e = __expf(v0 - mx) + __expf(v1 - mx) + __expf(v2 - mx) + __expf(v3 - mx);
  red[tid] = e;
  __syncthreads();
  for (int s = 128; s > 0; s >>= 1) {
    if (tid < s) red[tid] += red[tid + s];
    __syncthreads();
  }
  float ls = mx + logf(red[0]);
  p[tid] = v0 - ls;
  p[tid + 256] = v1 - ls;
  p[tid + 512] = v2 - ls;
  p[tid + 768] = v3 - ls;
}

// ---------------------------------------------------------------------------
// Host side
// ---------------------------------------------------------------------------
static void run_encoder(float* x, int B, int S, int L,
                        const float* qkv_w, const float* qkv_b,
                        const float* ow, const float* ob,
                        const float* f1w, const float* f1b,
                        const float* f2w, const float* f2b,
                        const float* l1s, const float* l1b,
                        const float* l2s, const float* l2b,
                        float* qkv, float* ctx, float* tmp, float* ff1,
                        hipStream_t stream) {
  int M = B * S;
  for (int l = 0; l < L; l++) {
    gemm_kernel<0><<<dim3(1536 / 64, M / 64), 256, 0, stream>>>(
        x, HD, qkv_w + (size_t)l * 1536 * HD, HD, qkv_b + (size_t)l * 1536,
        qkv, M, 1536, HD);
    attn_kernel<<<dim3(S, 8, B), 256, 0, stream>>>(qkv, ctx, S);
    gemm_kernel<0><<<dim3(HD / 64, M / 64), 256, 0, stream>>>(
        ctx, HD, ow + (size_t)l * HD * HD, HD, ob + (size_t)l * HD,
        tmp, M, HD, HD);
    add_ln_kernel<<<M, 256, 0, stream>>>(x, tmp, l1s + (size_t)l * HD,
                                         l1b + (size_t)l * HD);
    gemm_kernel<1><<<dim3(FF / 64, M / 64), 256, 0, stream>>>(
        x, HD, f1w + (size_t)l * FF * HD, HD, f1b + (size_t)l * FF,
        ff1, M, FF, HD);
    gemm_kernel<0><<<dim3(HD / 64, M / 64), 256, 0, stream>>>(
        ff1, FF, f2w + (size_t)l * HD * FF, FF, f2b + (size_t)l * HD,
        tmp, M, HD, FF);
    add_ln_kernel<<<M, 256, 0, stream>>>(x, tmp, l2s + (size_t)l * HD,
                                         l2b + (size_t)l * HD);
  }
}

extern "C" void kernel_launch(void* const* d_in, const int* in_sizes, int n_in,
                              void* d_out, int out_size, void* d_ws, size_t ws_size,
                              hipStream_t stream) {
  const int B = 4, T = 256, U = 64;
  const float* input_values = (const float*)d_in[0];
  const int* labels = (const int*)d_in[1];
  const float* a_lin_w = (const float*)d_in[4];
  const float* a_lin_b = (const float*)d_in[5];
  const float* a_pos = (const float*)d_in[6];
  const float* l_word = (const float*)d_in[7];
  const float* l_pos = (const float*)d_in[8];
  const float* joint_w = (const float*)d_in[9];
  const float* joint_b = (const float*)d_in[10];
  const float* out_w = (const float*)d_in[11];
  const float* out_b = (const float*)d_in[12];

  // audio layer weights: indices 13..24, label: 25..36
  const float* a_qkv_w = (const float*)d_in[13];
  const float* a_qkv_b = (const float*)d_in[14];
  const float* a_out_w = (const float*)d_in[15];
  const float* a_out_b = (const float*)d_in[16];
  const float* a_ff1_w = (const float*)d_in[17];
  const float* a_ff1_b = (const float*)d_in[18];
  const float* a_ff2_w = (const float*)d_in[19];
  const float* a_ff2_b = (const float*)d_in[20];
  const float* a_ln1_s = (const float*)d_in[21];
  const float* a_ln1_b = (const float*)d_in[22];
  const float* a_ln2_s = (const float*)d_in[23];
  const float* a_ln2_b = (const float*)d_in[24];
  const float* l_qkv_w = (const float*)d_in[25];
  const float* l_qkv_b = (const float*)d_in[26];
  const float* l_out_w = (const float*)d_in[27];
  const float* l_out_b = (const float*)d_in[28];
  const float* l_ff1_w = (const float*)d_in[29];
  const float* l_ff1_b = (const float*)d_in[30];
  const float* l_ff2_w = (const float*)d_in[31];
  const float* l_ff2_b = (const float*)d_in[32];
  const float* l_ln1_s = (const float*)d_in[33];
  const float* l_ln1_b = (const float*)d_in[34];
  const float* l_ln2_s = (const float*)d_in[35];
  const float* l_ln2_b = (const float*)d_in[36];

  float* ws = (float*)d_ws;
  // workspace layout (floats)
  float* xa  = ws;                 // 1024*512          = 524288
  float* xl  = xa + 524288;        // 256*512           = 131072
  float* qkv = xl + 131072;        // 1024*1536         = 1572864
  float* ctx = qkv + 1572864;      // 1024*512          = 524288
  float* tmp = ctx + 524288;       // 1024*512          = 524288
  float* ff1 = tmp + 524288;       // 1024*2048         = 2097152
  float* ha  = ff1 + 2097152;      // 1024*2048         = 2097152
  float* hl  = ha + 2097152;       // 256*2048          = 524288

  // ---- audio path ----
  embed_audio_kernel<<<B * T, 256, 0, stream>>>(input_values, a_lin_w, a_lin_b,
                                                a_pos, xa, T);
  run_encoder(xa, B, T, 12, a_qkv_w, a_qkv_b, a_out_w, a_out_b, a_ff1_w,
              a_ff1_b, a_ff2_w, a_ff2_b, a_ln1_s, a_ln1_b, a_ln2_s, a_ln2_b,
              qkv, ctx, tmp, ff1, stream);

  // ---- label path ----
  embed_label_kernel<<<B * U, 256, 0, stream>>>(labels, l_word, l_pos, xl, U);
  run_encoder(xl, B, U, 4, l_qkv_w, l_qkv_b, l_out_w, l_out_b, l_ff1_w,
              l_ff1_b, l_ff2_w, l_ff2_b, l_ln1_s, l_ln1_b, l_ln2_s, l_ln2_b,
              qkv, ctx, tmp, ff1, stream);

  // ---- joint ----
  // ha = av @ Wa^T (Wa = joint_w[:, :512], ld 1024)
  gemm_kernel<0><<<dim3(KJOINT / 64, (B * T) / 64), 256, 0, stream>>>(
      xa, HD, joint_w, 1024, nullptr, ha, B * T, KJOINT, HD);
  // hl = lv @ Wl^T + joint_b (Wl = joint_w[:, 512:], ld 1024)
  gemm_kernel<0><<<dim3(KJOINT / 64, (B * U) / 64), 256, 0, stream>>>(
      xl, HD, joint_w + HD, 1024, joint_b, hl, B * U, KJOINT, HD);

  joint_kernel<<<dim3(VOUT / 256, T, B), 256, 0, stream>>>(
      ha, hl, out_w, out_b, (float*)d_out, T, U);
  logsoftmax_kernel<<<B * T * U, 256, 0, stream>>>((float*)d_out);
}

// Round 2
// 6296.044 us; speedup vs baseline: 1.4928x; 1.4928x over previous
//
#include <hip/hip_runtime.h>
#include <cstddef>

#define HD 512
#define FF 2048
#define VOUT 1024
#define KJOINT 2048

typedef short bf16x8 __attribute__((ext_vector_type(8)));
typedef float f32x4 __attribute__((ext_vector_type(4)));

__device__ inline unsigned short f2bf(float f) {
  union { float f; unsigned u; } c{f};
  unsigned r = c.u + 0x7FFFu + ((c.u >> 16) & 1u);
  return (unsigned short)(r >> 16);
}
__device__ inline float bf2f(unsigned short h) {
  union { unsigned u; float f; } c{(unsigned)h << 16};
  return c.f;
}

// ---------------------------------------------------------------------------
// Embedding kernels
// ---------------------------------------------------------------------------
__global__ __launch_bounds__(256) void embed_audio_kernel(
    const float* __restrict__ inp,   // [B,80,T]
    const float* __restrict__ w,     // [512,80]
    const float* __restrict__ bias,  // [512]
    const float* __restrict__ pos,   // [P,512]
    float* __restrict__ x, int T) {
  int bt = blockIdx.x;
  int b = bt / T, t = bt - b * T;
  int tid = threadIdx.x;
  __shared__ __align__(16) float col[80];
  if (tid < 80) col[tid] = inp[((size_t)b * 80 + tid) * T + t];
  __syncthreads();
  for (int h = tid; h < HD; h += 256) {
    const float* wr = w + (size_t)h * 80;
    float acc = 0.f;
#pragma unroll
    for (int c = 0; c < 80; c++) acc += col[c] * wr[c];
    x[(size_t)bt * HD + h] = acc + bias[h] + pos[(size_t)t * HD + h];
  }
}

__global__ __launch_bounds__(256) void embed_label_kernel(
    const int* __restrict__ labels,  // [B,U]
    const float* __restrict__ word,  // [V,512]
    const float* __restrict__ pos,   // [P,512]
    float* __restrict__ y, int U) {
  int bu = blockIdx.x;
  int u = bu % U;
  int tid = threadIdx.x;
  int id = labels[bu];
  for (int h = tid; h < HD; h += 256)
    y[(size_t)bu * HD + h] = word[(size_t)id * HD + h] + pos[(size_t)u * HD + h];
}

// ---------------------------------------------------------------------------
// f32 -> bf16 conversion, 4 elements/thread, n % 1024 == 0
// ---------------------------------------------------------------------------
__global__ __launch_bounds__(256) void cvt_bf16_kernel(
    const float* __restrict__ in, unsigned short* __restrict__ out) {
  size_t i = ((size_t)blockIdx.x * 256 + threadIdx.x) * 4;
  float4 v = *(const float4*)(in + i);
  ushort4 o;
  o.x = f2bf(v.x); o.y = f2bf(v.y); o.z = f2bf(v.z); o.w = f2bf(v.w);
  *(ushort4*)(out + i) = o;
}

// ---------------------------------------------------------------------------
// Generic f32 GEMM: C[M,N] = act(A[M,K] @ B[N,K]^T + bias[N])
// 64x64 tile, K-step 16, [k][m] LDS layout, 256 threads, 4x4 per thread.
// ---------------------------------------------------------------------------
template <int ACT>
__global__ __launch_bounds__(256) void gemm_kernel(
    const float* __restrict__ A, int lda,
    const float* __restrict__ B, int ldb,
    const float* __restrict__ bias,
    float* __restrict__ C, int M, int N, int K) {
  __shared__ __align__(16) float As[16][64];
  __shared__ __align__(16) float Bs[16][64];
  int by = blockIdx.y * 64;  // m
  int bx = blockIdx.x * 64;  // n
  int tid = threadIdx.x;
  int tx = tid & 15, ty = tid >> 4;
  int lm = tid & 63, lkq = (tid >> 6) << 2;
  const float* Ap = A + (size_t)(by + lm) * lda + lkq;
  const float* Bp = B + (size_t)(bx + lm) * ldb + lkq;
  float acc[4][4] = {};
  for (int k0 = 0; k0 < K; k0 += 16) {
    float4 av = *(const float4*)(Ap + k0);
    float4 bv = *(const float4*)(Bp + k0);
    As[lkq + 0][lm] = av.x; As[lkq + 1][lm] = av.y;
    As[lkq + 2][lm] = av.z; As[lkq + 3][lm] = av.w;
    Bs[lkq + 0][lm] = bv.x; Bs[lkq + 1][lm] = bv.y;
    Bs[lkq + 2][lm] = bv.z; Bs[lkq + 3][lm] = bv.w;
    __syncthreads();
#pragma unroll
    for (int k = 0; k < 16; k++) {
      float4 a4 = *(const float4*)&As[k][ty << 2];
      float4 b4 = *(const float4*)&Bs[k][tx << 2];
      float a[4] = {a4.x, a4.y, a4.z, a4.w};
      float b[4] = {b4.x, b4.y, b4.z, b4.w};
#pragma unroll
      for (int i = 0; i < 4; i++)
#pragma unroll
        for (int j = 0; j < 4; j++) acc[i][j] = fmaf(a[i], b[j], acc[i][j]);
    }
    __syncthreads();
  }
  int n0 = bx + (tx << 2);
  float4 bi = bias ? *(const float4*)(bias + n0) : float4{0.f, 0.f, 0.f, 0.f};
#pragma unroll
  for (int i = 0; i < 4; i++) {
    int m = by + (ty << 2) + i;
    float4 v;
    v.x = acc[i][0] + bi.x; v.y = acc[i][1] + bi.y;
    v.z = acc[i][2] + bi.z; v.w = acc[i][3] + bi.w;
    if (ACT == 1) {
      v.x = fmaxf(v.x, 0.f); v.y = fmaxf(v.y, 0.f);
      v.z = fmaxf(v.z, 0.f); v.w = fmaxf(v.w, 0.f);
    }
    *(float4*)(C + (size_t)m * N + n0) = v;
  }
}

// ---------------------------------------------------------------------------
// Attention: one block per (q, head, batch). S <= 256. Mask is all-false.
// ---------------------------------------------------------------------------
__global__ __launch_bounds__(256) void attn_kernel(
    const float* __restrict__ qkv, float* __restrict__ ctx, int S) {
  int q = blockIdx.x, h = blockIdx.y, b = blockIdx.z;
  int tid = threadIdx.x;
  __shared__ __align__(16) float qs[64];
  __shared__ float red[256];
  __shared__ float p[256];
  __shared__ float cred[4][64];
  const float* base = qkv + (size_t)(b * S) * 1536;
  if (tid < 64) qs[tid] = base[(size_t)q * 1536 + h * 64 + tid];
  __syncthreads();
  float score = -1e30f;
  if (tid < S) {
    const float4* k4 = (const float4*)(base + (size_t)tid * 1536 + 512 + h * 64);
    const float4* q4 = (const float4*)qs;
    float acc = 0.f;
#pragma unroll
    for (int d = 0; d < 16; d++) {
      float4 kk = k4[d], qq = q4[d];
      acc += qq.x * kk.x + qq.y * kk.y + qq.z * kk.z + qq.w * kk.w;
    }
    score = acc * 0.125f;
  }
  red[tid] = score;
  __syncthreads();
  for (int s = 128; s > 0; s >>= 1) {
    if (tid < s) red[tid] = fmaxf(red[tid], red[tid + s]);
    __syncthreads();
  }
  float mx = red[0];
  __syncthreads();
  float e = (tid < S) ? __expf(score - mx) : 0.f;
  red[tid] = e;
  __syncthreads();
  for (int s = 128; s > 0; s >>= 1) {
    if (tid < s) red[tid] += red[tid + s];
    __syncthreads();
  }
  float inv = 1.f / red[0];
  p[tid] = e * inv;
  __syncthreads();
  int d = tid & 63, part = tid >> 6;
  float acc = 0.f;
  for (int j = part; j < S; j += 4)
    acc += p[j] * base[(size_t)j * 1536 + 1024 + h * 64 + d];
  cred[part][d] = acc;
  __syncthreads();
  if (tid < 64) {
    float c = cred[0][tid] + cred[1][tid] + cred[2][tid] + cred[3][tid];
    ctx[((size_t)(b * S + q)) * HD + h * 64 + tid] = c;
  }
}

// ---------------------------------------------------------------------------
// Residual add + LayerNorm, in place on x. One block per row, H=512.
// ---------------------------------------------------------------------------
__global__ __launch_bounds__(256) void add_ln_kernel(
    float* __restrict__ x, const float* __restrict__ y,
    const float* __restrict__ s, const float* __restrict__ bsh) {
  int row = blockIdx.x, tid = threadIdx.x;
  float* xr = x + (size_t)row * HD;
  const float* yr = y + (size_t)row * HD;
  float v0 = xr[tid] + yr[tid];
  float v1 = xr[tid + 256] + yr[tid + 256];
  __shared__ float rs_[256], rq_[256];
  rs_[tid] = v0 + v1;
  rq_[tid] = v0 * v0 + v1 * v1;
  __syncthreads();
  for (int st = 128; st > 0; st >>= 1) {
    if (tid < st) { rs_[tid] += rs_[tid + st]; rq_[tid] += rq_[tid + st]; }
    __syncthreads();
  }
  float mean = rs_[0] * (1.f / HD);
  float var = rq_[0] * (1.f / HD) - mean * mean;
  float rstd = rsqrtf(var + 1e-5f);
  xr[tid] = (v0 - mean) * rstd * s[tid] + bsh[tid];
  xr[tid + 256] = (v1 - mean) * rstd * s[tid + 256] + bsh[tid + 256];
}

// ---------------------------------------------------------------------------
// Joint via bf16 MFMA.
// Output GEMM: M=65536 (b,t,u), N=1024 (v), K=2048.
// Block: 128 rows (2 t-groups x 64 u) x 256 cols, 512 threads = 8 waves,
// each wave one 64x64 sub-tile (4x4 fragments of 16x16x32).
// A generated on the fly: tanh(ha_bf[t] + hl_bf[u]) -> bf16.
// LDS rows padded to 40 shorts (80B) - all DS accesses at bank floor.
// ---------------------------------------------------------------------------
#define JM 128
#define JN 256
__global__ __launch_bounds__(512) void joint_mfma_kernel(
    const unsigned short* __restrict__ ha,  // [B*T,2048] bf16
    const unsigned short* __restrict__ hl,  // [B*U,2048] bf16
    const unsigned short* __restrict__ W,   // [1024,2048] bf16
    const float* __restrict__ wb,           // [1024]
    float* __restrict__ out, int T, int U) {
  __shared__ short As[JM * 40];
  __shared__ short Bs[JN * 40];
  int tid = threadIdx.x;
  int m0 = blockIdx.y * JM;
  int vt = blockIdx.x * JN;
  int b = m0 >> 14;            // T*U = 16384
  int t0 = (m0 >> 6) & 255;
  int lane = tid & 63, w = tid >> 6;
  int wr = w >> 2, wc = w & 3;

  // A staging: thread -> (row 0..127, quarter 0..3) = 8 k each
  int srow = tid >> 2, sq = tid & 3;
  int u_s = srow & 63, tt = t0 + (srow >> 6);
  const unsigned short* ha_p = ha + ((size_t)(b * T + tt)) * KJOINT + sq * 8;
  const unsigned short* hl_p = hl + ((size_t)(b * U + u_s)) * KJOINT + sq * 8;
  short* As_w = As + srow * 40 + sq * 8;
  // B staging: thread -> (row 0..255, half 0..1) = 16 k each
  int brow = tid >> 1, bh = tid & 1;
  const unsigned short* W_p = W + ((size_t)(vt + brow)) * KJOINT + bh * 16;
  short* Bs_w = Bs + brow * 40 + bh * 16;

  f32x4 acc[4][4] = {};
  const short* As_r = As + (wr * 64 + (lane & 15)) * 40 + ((lane >> 4) * 8);
  const short* Bs_r = Bs + (wc * 64 + (lane & 15)) * 40 + ((lane >> 4) * 8);

  for (int k0 = 0; k0 < KJOINT; k0 += 32) {
    bf16x8 av = *(const bf16x8*)(ha_p + k0);
    bf16x8 lv = *(const bf16x8*)(hl_p + k0);
    bf16x8 w0 = *(const bf16x8*)(W_p + k0);
    bf16x8 w1 = *(const bf16x8*)(W_p + k0 + 8);
    short hv[8];
#pragma unroll
    for (int j = 0; j < 8; j++) {
      float x = bf2f((unsigned short)av[j]) + bf2f((unsigned short)lv[j]);
      hv[j] = (short)f2bf(tanhf(x));
    }
    __syncthreads();
    *(bf16x8*)As_w = *(const bf16x8*)hv;
    *(bf16x8*)Bs_w = w0;
    *(bf16x8*)(Bs_w + 8) = w1;
    __syncthreads();
    bf16x8 afr[4], bfr[4];
#pragma unroll
    for (int i = 0; i < 4; i++) {
      afr[i] = *(const bf16x8*)(As_r + i * 16 * 40);
      bfr[i] = *(const bf16x8*)(Bs_r + i * 16 * 40);
    }
#pragma unroll
    for (int mi = 0; mi < 4; mi++)
#pragma unroll
      for (int ni = 0; ni < 4; ni++)
        acc[mi][ni] = __builtin_amdgcn_mfma_f32_16x16x32_bf16(
            afr[mi], bfr[ni], acc[mi][ni], 0, 0, 0);
  }

  // C/D layout: col = lane&15, row = (lane>>4)*4 + j
  int colbase = vt + wc * 64 + (lane & 15);
  int rowbase = m0 + wr * 64 + ((lane >> 4) * 4);
#pragma unroll
  for (int ni = 0; ni < 4; ni++) {
    float bias = wb[colbase + ni * 16];
#pragma unroll
    for (int mi = 0; mi < 4; mi++) {
#pragma unroll
      for (int j = 0; j < 4; j++) {
        int m = rowbase + mi * 16 + j;
        out[(size_t)m * VOUT + colbase + ni * 16] = acc[mi][ni][j] + bias;
      }
    }
  }
}

// ---------------------------------------------------------------------------
// In-place log_softmax over last dim (1024). One block per row.
// ---------------------------------------------------------------------------
__global__ __launch_bounds__(256) void logsoftmax_kernel(float* __restrict__ out) {
  size_t row = blockIdx.x;
  float* p = out + row * VOUT;
  int tid = threadIdx.x;
  float v0 = p[tid], v1 = p[tid + 256], v2 = p[tid + 512], v3 = p[tid + 768];
  __shared__ float red[256];
  float m = fmaxf(fmaxf(v0, v1), fmaxf(v2, v3));
  red[tid] = m;
  __syncthreads();
  for (int s = 128; s > 0; s >>= 1) {
    if (tid < s) red[tid] = fmaxf(red[tid], red[tid + s]);
    __syncthreads();
  }
  float mx = red[0];
  __syncthreads();
  float e = __expf(v0 - mx) + __expf(v1 - mx) + __expf(v2 - mx) + __expf(v3 - mx);
  red[tid] = e;
  __syncthreads();
  for (int s = 128; s > 0; s >>= 1) {
    if (tid < s) red[tid] += red[tid + s];
    __syncthreads();
  }
  float ls = mx + logf(red[0]);
  p[tid] = v0 - ls;
  p[tid + 256] = v1 - ls;
  p[tid + 512] = v2 - ls;
  p[tid + 768] = v3 - ls;
}

// ---------------------------------------------------------------------------
// Host side
// ---------------------------------------------------------------------------
static void run_encoder(float* x, int B, int S, int L,
                        const float* qkv_w, const float* qkv_b,
                        const float* ow, const float* ob,
                        const float* f1w, const float* f1b,
                        const float* f2w, const float* f2b,
                        const float* l1s, const float* l1b,
                        const float* l2s, const float* l2b,
                        float* qkv, float* ctx, float* tmp, float* ff1,
                        hipStream_t stream) {
  int M = B * S;
  for (int l = 0; l < L; l++) {
    gemm_kernel<0><<<dim3(1536 / 64, M / 64), 256, 0, stream>>>(
        x, HD, qkv_w + (size_t)l * 1536 * HD, HD, qkv_b + (size_t)l * 1536,
        qkv, M, 1536, HD);
    attn_kernel<<<dim3(S, 8, B), 256, 0, stream>>>(qkv, ctx, S);
    gemm_kernel<0><<<dim3(HD / 64, M / 64), 256, 0, stream>>>(
        ctx, HD, ow + (size_t)l * HD * HD, HD, ob + (size_t)l * HD,
        tmp, M, HD, HD);
    add_ln_kernel<<<M, 256, 0, stream>>>(x, tmp, l1s + (size_t)l * HD,
                                         l1b + (size_t)l * HD);
    gemm_kernel<1><<<dim3(FF / 64, M / 64), 256, 0, stream>>>(
        x, HD, f1w + (size_t)l * FF * HD, HD, f1b + (size_t)l * FF,
        ff1, M, FF, HD);
    gemm_kernel<0><<<dim3(HD / 64, M / 64), 256, 0, stream>>>(
        ff1, FF, f2w + (size_t)l * HD * FF, FF, f2b + (size_t)l * HD,
        tmp, M, HD, FF);
    add_ln_kernel<<<M, 256, 0, stream>>>(x, tmp, l2s + (size_t)l * HD,
                                         l2b + (size_t)l * HD);
  }
}

extern "C" void kernel_launch(void* const* d_in, const int* in_sizes, int n_in,
                              void* d_out, int out_size, void* d_ws, size_t ws_size,
                              hipStream_t stream) {
  const int B = 4, T = 256, U = 64;
  const float* input_values = (const float*)d_in[0];
  const int* labels = (const int*)d_in[1];
  const float* a_lin_w = (const float*)d_in[4];
  const float* a_lin_b = (const float*)d_in[5];
  const float* a_pos = (const float*)d_in[6];
  const float* l_word = (const float*)d_in[7];
  const float* l_pos = (const float*)d_in[8];
  const float* joint_w = (const float*)d_in[9];
  const float* joint_b = (const float*)d_in[10];
  const float* out_w = (const float*)d_in[11];
  const float* out_b = (const float*)d_in[12];

  const float* a_qkv_w = (const float*)d_in[13];
  const float* a_qkv_b = (const float*)d_in[14];
  const float* a_out_w = (const float*)d_in[15];
  const float* a_out_b = (const float*)d_in[16];
  const float* a_ff1_w = (const float*)d_in[17];
  const float* a_ff1_b = (const float*)d_in[18];
  const float* a_ff2_w = (const float*)d_in[19];
  const float* a_ff2_b = (const float*)d_in[20];
  const float* a_ln1_s = (const float*)d_in[21];
  const float* a_ln1_b = (const float*)d_in[22];
  const float* a_ln2_s = (const float*)d_in[23];
  const float* a_ln2_b = (const float*)d_in[24];
  const float* l_qkv_w = (const float*)d_in[25];
  const float* l_qkv_b = (const float*)d_in[26];
  const float* l_out_w = (const float*)d_in[27];
  const float* l_out_b = (const float*)d_in[28];
  const float* l_ff1_w = (const float*)d_in[29];
  const float* l_ff1_b = (const float*)d_in[30];
  const float* l_ff2_w = (const float*)d_in[31];
  const float* l_ff2_b = (const float*)d_in[32];
  const float* l_ln1_s = (const float*)d_in[33];
  const float* l_ln1_b = (const float*)d_in[34];
  const float* l_ln2_s = (const float*)d_in[35];
  const float* l_ln2_b = (const float*)d_in[36];

  float* ws = (float*)d_ws;
  float* xa  = ws;                 // 1024*512
  float* xl  = xa + 524288;        // 256*512
  float* qkv = xl + 131072;        // 1024*1536
  float* ctx = qkv + 1572864;      // 1024*512
  float* tmp = ctx + 524288;       // 1024*512
  float* ff1 = tmp + 524288;       // 1024*2048
  float* ha  = ff1 + 2097152;      // 1024*2048
  float* hl  = ha + 2097152;       // 256*2048
  unsigned short* bfarea = (unsigned short*)(hl + 524288);
  unsigned short* Wb    = bfarea;              // 1024*2048
  unsigned short* ha_bf = Wb + 2097152;        // 1024*2048
  unsigned short* hl_bf = ha_bf + 2097152;     // 256*2048

  // ---- audio path ----
  embed_audio_kernel<<<B * T, 256, 0, stream>>>(input_values, a_lin_w, a_lin_b,
                                                a_pos, xa, T);
  run_encoder(xa, B, T, 12, a_qkv_w, a_qkv_b, a_out_w, a_out_b, a_ff1_w,
              a_ff1_b, a_ff2_w, a_ff2_b, a_ln1_s, a_ln1_b, a_ln2_s, a_ln2_b,
              qkv, ctx, tmp, ff1, stream);

  // ---- label path ----
  embed_label_kernel<<<B * U, 256, 0, stream>>>(labels, l_word, l_pos, xl, U);
  run_encoder(xl, B, U, 4, l_qkv_w, l_qkv_b, l_out_w, l_out_b, l_ff1_w,
              l_ff1_b, l_ff2_w, l_ff2_b, l_ln1_s, l_ln1_b, l_ln2_s, l_ln2_b,
              qkv, ctx, tmp, ff1, stream);

  // ---- joint projections (f32) ----
  gemm_kernel<0><<<dim3(KJOINT / 64, (B * T) / 64), 256, 0, stream>>>(
      xa, HD, joint_w, 1024, nullptr, ha, B * T, KJOINT, HD);
  gemm_kernel<0><<<dim3(KJOINT / 64, (B * U) / 64), 256, 0, stream>>>(
      xl, HD, joint_w + HD, 1024, joint_b, hl, B * U, KJOINT, HD);

  // ---- bf16 conversions ----
  cvt_bf16_kernel<<<(VOUT * KJOINT) / 1024, 256, 0, stream>>>(out_w, Wb);
  cvt_bf16_kernel<<<(B * T * KJOINT) / 1024, 256, 0, stream>>>(ha, ha_bf);
  cvt_bf16_kernel<<<(B * U * KJOINT) / 1024, 256, 0, stream>>>(hl, hl_bf);

  // ---- joint MFMA + log-softmax ----
  joint_mfma_kernel<<<dim3(VOUT / JN, (B * T * U) / JM), 512, 0, stream>>>(
      ha_bf, hl_bf, Wb, out_b, (float*)d_out, T, U);
  logsoftmax_kernel<<<B * T * U, 256, 0, stream>>>((float*)d_out);
}

// Round 3
// 4770.963 us; speedup vs baseline: 1.9700x; 1.3197x over previous
//
#include <hip/hip_runtime.h>
#include <cstddef>

#define HD 512
#define FF 2048
#define VOUT 1024
#define KJOINT 2048

typedef short bf16x8 __attribute__((ext_vector_type(8)));
typedef float f32x4 __attribute__((ext_vector_type(4)));

__device__ inline unsigned short f2bf(float f) {
  union { float f; unsigned u; } c{f};
  unsigned r = c.u + 0x7FFFu + ((c.u >> 16) & 1u);
  return (unsigned short)(r >> 16);
}
__device__ inline float bf2f(unsigned short h) {
  union { unsigned u; float f; } c{(unsigned)h << 16};
  return c.f;
}
__device__ inline float fast_tanh(float x) {
  float e = __expf(2.f * x);
  return 1.f - 2.f / (e + 1.f);
}

// ---------------------------------------------------------------------------
// Embedding kernels
// ---------------------------------------------------------------------------
__global__ __launch_bounds__(256) void embed_audio_kernel(
    const float* __restrict__ inp,   // [B,80,T]
    const float* __restrict__ w,     // [512,80]
    const float* __restrict__ bias,  // [512]
    const float* __restrict__ pos,   // [P,512]
    float* __restrict__ x, int T) {
  int bt = blockIdx.x;
  int b = bt / T, t = bt - b * T;
  int tid = threadIdx.x;
  __shared__ __align__(16) float col[80];
  if (tid < 80) col[tid] = inp[((size_t)b * 80 + tid) * T + t];
  __syncthreads();
  for (int h = tid; h < HD; h += 256) {
    const float* wr = w + (size_t)h * 80;
    float acc = 0.f;
#pragma unroll
    for (int c = 0; c < 80; c++) acc += col[c] * wr[c];
    x[(size_t)bt * HD + h] = acc + bias[h] + pos[(size_t)t * HD + h];
  }
}

__global__ __launch_bounds__(256) void embed_label_kernel(
    const int* __restrict__ labels,  // [B,U]
    const float* __restrict__ word,  // [V,512]
    const float* __restrict__ pos,   // [P,512]
    float* __restrict__ y, int U) {
  int bu = blockIdx.x;
  int u = bu % U;
  int tid = threadIdx.x;
  int id = labels[bu];
  for (int h = tid; h < HD; h += 256)
    y[(size_t)bu * HD + h] = word[(size_t)id * HD + h] + pos[(size_t)u * HD + h];
}

// ---------------------------------------------------------------------------
// f32 -> bf16 conversion, 4 elements/thread, n % 1024 == 0
// ---------------------------------------------------------------------------
__global__ __launch_bounds__(256) void cvt_bf16_kernel(
    const float* __restrict__ in, unsigned short* __restrict__ out) {
  size_t i = ((size_t)blockIdx.x * 256 + threadIdx.x) * 4;
  float4 v = *(const float4*)(in + i);
  ushort4 o;
  o.x = f2bf(v.x); o.y = f2bf(v.y); o.z = f2bf(v.z); o.w = f2bf(v.w);
  *(ushort4*)(out + i) = o;
}

// ---------------------------------------------------------------------------
// bf16 MFMA GEMM: C[M,N] = act(A[M,K] @ B[N,K]^T + bias[N])
// A, B are f32 in global; converted to bf16 during LDS staging.
// Tile 128x128, K-step 32, 256 threads = 4 waves, each wave 64x64
// (4x4 fragments of 16x16x32). M%128==0, N%128==0, K%32==0.
// ---------------------------------------------------------------------------
template <int ACT, int OUT_BF16>
__global__ __launch_bounds__(256) void gemm_bf16_kernel(
    const float* __restrict__ A, int lda,
    const float* __restrict__ Bw, int ldb,
    const float* __restrict__ bias,
    void* __restrict__ Cout, int ldc, int M, int N, int K) {
  __shared__ short As[128 * 40];
  __shared__ short Bs[128 * 40];
  int tid = threadIdx.x;
  int by = blockIdx.y * 128;
  int bx = blockIdx.x * 128;
  int lane = tid & 63, w = tid >> 6;
  int wr = w >> 1, wc = w & 1;

  // staging map: thread -> (row = tid>>3 + 32*p, k = (tid&7)*4), p = 0..3
  int srow = tid >> 3;
  int sk = (tid & 7) * 4;
  const float* Ab = A + (size_t)(by + srow) * lda + sk;
  const float* Bb = Bw + (size_t)(bx + srow) * ldb + sk;

  f32x4 acc[4][4] = {};
  const short* As_r = As + (wr * 64 + (lane & 15)) * 40 + ((lane >> 4) * 8);
  const short* Bs_r = Bs + (wc * 64 + (lane & 15)) * 40 + ((lane >> 4) * 8);

  for (int k0 = 0; k0 < K; k0 += 32) {
    float4 a[4], b[4];
#pragma unroll
    for (int p = 0; p < 4; p++) {
      a[p] = *(const float4*)(Ab + (size_t)(p * 32) * lda + k0);
      b[p] = *(const float4*)(Bb + (size_t)(p * 32) * ldb + k0);
    }
    __syncthreads();
#pragma unroll
    for (int p = 0; p < 4; p++) {
      ushort4 pa{f2bf(a[p].x), f2bf(a[p].y), f2bf(a[p].z), f2bf(a[p].w)};
      ushort4 pb{f2bf(b[p].x), f2bf(b[p].y), f2bf(b[p].z), f2bf(b[p].w)};
      *(ushort4*)(As + (srow + p * 32) * 40 + sk) = pa;
      *(ushort4*)(Bs + (srow + p * 32) * 40 + sk) = pb;
    }
    __syncthreads();
    bf16x8 afr[4], bfr[4];
#pragma unroll
    for (int i = 0; i < 4; i++) {
      afr[i] = *(const bf16x8*)(As_r + i * 16 * 40);
      bfr[i] = *(const bf16x8*)(Bs_r + i * 16 * 40);
    }
#pragma unroll
    for (int mi = 0; mi < 4; mi++)
#pragma unroll
      for (int ni = 0; ni < 4; ni++)
        acc[mi][ni] = __builtin_amdgcn_mfma_f32_16x16x32_bf16(
            afr[mi], bfr[ni], acc[mi][ni], 0, 0, 0);
  }

  int colbase = bx + wc * 64 + (lane & 15);
  int rowbase = by + wr * 64 + ((lane >> 4) * 4);
#pragma unroll
  for (int ni = 0; ni < 4; ni++) {
    int col = colbase + ni * 16;
    float bi = bias ? bias[col] : 0.f;
#pragma unroll
    for (int mi = 0; mi < 4; mi++) {
#pragma unroll
      for (int j = 0; j < 4; j++) {
        int row = rowbase + mi * 16 + j;
        float v = acc[mi][ni][j] + bi;
        if (ACT == 1) v = fmaxf(v, 0.f);
        if (OUT_BF16)
          ((unsigned short*)Cout)[(size_t)row * ldc + col] = f2bf(v);
        else
          ((float*)Cout)[(size_t)row * ldc + col] = v;
      }
    }
  }
}

// ---------------------------------------------------------------------------
// Attention: one block per (q, head, batch). S <= 256. Mask is all-false.
// ---------------------------------------------------------------------------
__global__ __launch_bounds__(256) void attn_kernel(
    const float* __restrict__ qkv, float* __restrict__ ctx, int S) {
  int q = blockIdx.x, h = blockIdx.y, b = blockIdx.z;
  int tid = threadIdx.x;
  __shared__ __align__(16) float qs[64];
  __shared__ float red[256];
  __shared__ float p[256];
  __shared__ float cred[4][64];
  const float* base = qkv + (size_t)(b * S) * 1536;
  if (tid < 64) qs[tid] = base[(size_t)q * 1536 + h * 64 + tid];
  __syncthreads();
  float score = -1e30f;
  if (tid < S) {
    const float4* k4 = (const float4*)(base + (size_t)tid * 1536 + 512 + h * 64);
    const float4* q4 = (const float4*)qs;
    float acc = 0.f;
#pragma unroll
    for (int d = 0; d < 16; d++) {
      float4 kk = k4[d], qq = q4[d];
      acc += qq.x * kk.x + qq.y * kk.y + qq.z * kk.z + qq.w * kk.w;
    }
    score = acc * 0.125f;
  }
  red[tid] = score;
  __syncthreads();
  for (int s = 128; s > 0; s >>= 1) {
    if (tid < s) red[tid] = fmaxf(red[tid], red[tid + s]);
    __syncthreads();
  }
  float mx = red[0];
  __syncthreads();
  float e = (tid < S) ? __expf(score - mx) : 0.f;
  red[tid] = e;
  __syncthreads();
  for (int s = 128; s > 0; s >>= 1) {
    if (tid < s) red[tid] += red[tid + s];
    __syncthreads();
  }
  float inv = 1.f / red[0];
  p[tid] = e * inv;
  __syncthreads();
  int d = tid & 63, part = tid >> 6;
  float acc = 0.f;
  for (int j = part; j < S; j += 4)
    acc += p[j] * base[(size_t)j * 1536 + 1024 + h * 64 + d];
  cred[part][d] = acc;
  __syncthreads();
  if (tid < 64) {
    float c = cred[0][tid] + cred[1][tid] + cred[2][tid] + cred[3][tid];
    ctx[((size_t)(b * S + q)) * HD + h * 64 + tid] = c;
  }
}

// ---------------------------------------------------------------------------
// Residual add + LayerNorm, in place on x. One block per row, H=512.
// ---------------------------------------------------------------------------
__global__ __launch_bounds__(256) void add_ln_kernel(
    float* __restrict__ x, const float* __restrict__ y,
    const float* __restrict__ s, const float* __restrict__ bsh) {
  int row = blockIdx.x, tid = threadIdx.x;
  float* xr = x + (size_t)row * HD;
  const float* yr = y + (size_t)row * HD;
  float v0 = xr[tid] + yr[tid];
  float v1 = xr[tid + 256] + yr[tid + 256];
  __shared__ float rs_[256], rq_[256];
  rs_[tid] = v0 + v1;
  rq_[tid] = v0 * v0 + v1 * v1;
  __syncthreads();
  for (int st = 128; st > 0; st >>= 1) {
    if (tid < st) { rs_[tid] += rs_[tid + st]; rq_[tid] += rq_[tid + st]; }
    __syncthreads();
  }
  float mean = rs_[0] * (1.f / HD);
  float var = rq_[0] * (1.f / HD) - mean * mean;
  float rstd = rsqrtf(var + 1e-5f);
  xr[tid] = (v0 - mean) * rstd * s[tid] + bsh[tid];
  xr[tid + 256] = (v1 - mean) * rstd * s[tid + 256] + bsh[tid + 256];
}

// ---------------------------------------------------------------------------
// Joint via bf16 MFMA. M=65536 (b,t,u), N=1024 (v), K=2048.
// Block: 128 rows x 256 cols, 512 threads = 8 waves, wave = 64x64 sub-tile.
// A generated on the fly: fast_tanh(ha_bf[t] + hl_bf[u]) -> bf16.
// ---------------------------------------------------------------------------
#define JM 128
#define JN 256
__global__ __launch_bounds__(512) void joint_mfma_kernel(
    const unsigned short* __restrict__ ha,  // [B*T,2048] bf16
    const unsigned short* __restrict__ hl,  // [B*U,2048] bf16
    const unsigned short* __restrict__ W,   // [1024,2048] bf16
    const float* __restrict__ wb,           // [1024]
    float* __restrict__ out, int T, int U) {
  __shared__ short As[JM * 40];
  __shared__ short Bs[JN * 40];
  int tid = threadIdx.x;
  int m0 = blockIdx.y * JM;
  int vt = blockIdx.x * JN;
  int b = m0 >> 14;            // T*U = 16384
  int t0 = (m0 >> 6) & 255;
  int lane = tid & 63, w = tid >> 6;
  int wr = w >> 2, wc = w & 3;

  int srow = tid >> 2, sq = tid & 3;
  int u_s = srow & 63, tt = t0 + (srow >> 6);
  const unsigned short* ha_p = ha + ((size_t)(b * T + tt)) * KJOINT + sq * 8;
  const unsigned short* hl_p = hl + ((size_t)(b * U + u_s)) * KJOINT + sq * 8;
  short* As_w = As + srow * 40 + sq * 8;
  int brow = tid >> 1, bh = tid & 1;
  const unsigned short* W_p = W + ((size_t)(vt + brow)) * KJOINT + bh * 16;
  short* Bs_w = Bs + brow * 40 + bh * 16;

  f32x4 acc[4][4] = {};
  const short* As_r = As + (wr * 64 + (lane & 15)) * 40 + ((lane >> 4) * 8);
  const short* Bs_r = Bs + (wc * 64 + (lane & 15)) * 40 + ((lane >> 4) * 8);

  for (int k0 = 0; k0 < KJOINT; k0 += 32) {
    bf16x8 av = *(const bf16x8*)(ha_p + k0);
    bf16x8 lv = *(const bf16x8*)(hl_p + k0);
    bf16x8 w0 = *(const bf16x8*)(W_p + k0);
    bf16x8 w1 = *(const bf16x8*)(W_p + k0 + 8);
    short hv[8];
#pragma unroll
    for (int j = 0; j < 8; j++) {
      float x = bf2f((unsigned short)av[j]) + bf2f((unsigned short)lv[j]);
      hv[j] = (short)f2bf(fast_tanh(x));
    }
    __syncthreads();
    *(bf16x8*)As_w = *(const bf16x8*)hv;
    *(bf16x8*)Bs_w = w0;
    *(bf16x8*)(Bs_w + 8) = w1;
    __syncthreads();
    bf16x8 afr[4], bfr[4];
#pragma unroll
    for (int i = 0; i < 4; i++) {
      afr[i] = *(const bf16x8*)(As_r + i * 16 * 40);
      bfr[i] = *(const bf16x8*)(Bs_r + i * 16 * 40);
    }
#pragma unroll
    for (int mi = 0; mi < 4; mi++)
#pragma unroll
      for (int ni = 0; ni < 4; ni++)
        acc[mi][ni] = __builtin_amdgcn_mfma_f32_16x16x32_bf16(
            afr[mi], bfr[ni], acc[mi][ni], 0, 0, 0);
  }

  int colbase = vt + wc * 64 + (lane & 15);
  int rowbase = m0 + wr * 64 + ((lane >> 4) * 4);
#pragma unroll
  for (int ni = 0; ni < 4; ni++) {
    float bias = wb[colbase + ni * 16];
#pragma unroll
    for (int mi = 0; mi < 4; mi++) {
#pragma unroll
      for (int j = 0; j < 4; j++) {
        int m = rowbase + mi * 16 + j;
        out[(size_t)m * VOUT + colbase + ni * 16] = acc[mi][ni][j] + bias;
      }
    }
  }
}

// ---------------------------------------------------------------------------
// In-place log_softmax over last dim (1024). One block per row.
// ---------------------------------------------------------------------------
__global__ __launch_bounds__(256) void logsoftmax_kernel(float* __restrict__ out) {
  size_t row = blockIdx.x;
  float* p = out + row * VOUT;
  int tid = threadIdx.x;
  float v0 = p[tid], v1 = p[tid + 256], v2 = p[tid + 512], v3 = p[tid + 768];
  __shared__ float red[256];
  float m = fmaxf(fmaxf(v0, v1), fmaxf(v2, v3));
  red[tid] = m;
  __syncthreads();
  for (int s = 128; s > 0; s >>= 1) {
    if (tid < s) red[tid] = fmaxf(red[tid], red[tid + s]);
    __syncthreads();
  }
  float mx = red[0];
  __syncthreads();
  float e = __expf(v0 - mx) + __expf(v1 - mx) + __expf(v2 - mx) + __expf(v3 - mx);
  red[tid] = e;
  __syncthreads();
  for (int s = 128; s > 0; s >>= 1) {
    if (tid < s) red[tid] += red[tid + s];
    __syncthreads();
  }
  float ls = mx + logf(red[0]);
  p[tid] = v0 - ls;
  p[tid + 256] = v1 - ls;
  p[tid + 512] = v2 - ls;
  p[tid + 768] = v3 - ls;
}

// ---------------------------------------------------------------------------
// Host side
// ---------------------------------------------------------------------------
static void run_encoder(float* x, int B, int S, int L,
                        const float* qkv_w, const float* qkv_b,
                        const float* ow, const float* ob,
                        const float* f1w, const float* f1b,
                        const float* f2w, const float* f2b,
                        const float* l1s, const float* l1b,
                        const float* l2s, const float* l2b,
                        float* qkv, float* ctx, float* tmp, float* ff1,
                        hipStream_t stream) {
  int M = B * S;
  for (int l = 0; l < L; l++) {
    gemm_bf16_kernel<0, 0><<<dim3(1536 / 128, M / 128), 256, 0, stream>>>(
        x, HD, qkv_w + (size_t)l * 1536 * HD, HD, qkv_b + (size_t)l * 1536,
        qkv, 1536, M, 1536, HD);
    attn_kernel<<<dim3(S, 8, B), 256, 0, stream>>>(qkv, ctx, S);
    gemm_bf16_kernel<0, 0><<<dim3(HD / 128, M / 128), 256, 0, stream>>>(
        ctx, HD, ow + (size_t)l * HD * HD, HD, ob + (size_t)l * HD,
        tmp, HD, M, HD, HD);
    add_ln_kernel<<<M, 256, 0, stream>>>(x, tmp, l1s + (size_t)l * HD,
                                         l1b + (size_t)l * HD);
    gemm_bf16_kernel<1, 0><<<dim3(FF / 128, M / 128), 256, 0, stream>>>(
        x, HD, f1w + (size_t)l * FF * HD, HD, f1b + (size_t)l * FF,
        ff1, FF, M, FF, HD);
    gemm_bf16_kernel<0, 0><<<dim3(HD / 128, M / 128), 256, 0, stream>>>(
        ff1, FF, f2w + (size_t)l * HD * FF, FF, f2b + (size_t)l * HD,
        tmp, HD, M, HD, FF);
    add_ln_kernel<<<M, 256, 0, stream>>>(x, tmp, l2s + (size_t)l * HD,
                                         l2b + (size_t)l * HD);
  }
}

extern "C" void kernel_launch(void* const* d_in, const int* in_sizes, int n_in,
                              void* d_out, int out_size, void* d_ws, size_t ws_size,
                              hipStream_t stream) {
  const int B = 4, T = 256, U = 64;
  const float* input_values = (const float*)d_in[0];
  const int* labels = (const int*)d_in[1];
  const float* a_lin_w = (const float*)d_in[4];
  const float* a_lin_b = (const float*)d_in[5];
  const float* a_pos = (const float*)d_in[6];
  const float* l_word = (const float*)d_in[7];
  const float* l_pos = (const float*)d_in[8];
  const float* joint_w = (const float*)d_in[9];
  const float* joint_b = (const float*)d_in[10];
  const float* out_w = (const float*)d_in[11];
  const float* out_b = (const float*)d_in[12];

  const float* a_qkv_w = (const float*)d_in[13];
  const float* a_qkv_b = (const float*)d_in[14];
  const float* a_out_w = (const float*)d_in[15];
  const float* a_out_b = (const float*)d_in[16];
  const float* a_ff1_w = (const float*)d_in[17];
  const float* a_ff1_b = (const float*)d_in[18];
  const float* a_ff2_w = (const float*)d_in[19];
  const float* a_ff2_b = (const float*)d_in[20];
  const float* a_ln1_s = (const float*)d_in[21];
  const float* a_ln1_b = (const float*)d_in[22];
  const float* a_ln2_s = (const float*)d_in[23];
  const float* a_ln2_b = (const float*)d_in[24];
  const float* l_qkv_w = (const float*)d_in[25];
  const float* l_qkv_b = (const float*)d_in[26];
  const float* l_out_w = (const float*)d_in[27];
  const float* l_out_b = (const float*)d_in[28];
  const float* l_ff1_w = (const float*)d_in[29];
  const float* l_ff1_b = (const float*)d_in[30];
  const float* l_ff2_w = (const float*)d_in[31];
  const float* l_ff2_b = (const float*)d_in[32];
  const float* l_ln1_s = (const float*)d_in[33];
  const float* l_ln1_b = (const float*)d_in[34];
  const float* l_ln2_s = (const float*)d_in[35];
  const float* l_ln2_b = (const float*)d_in[36];

  float* ws = (float*)d_ws;
  float* xa  = ws;                 // 1024*512
  float* xl  = xa + 524288;        // 256*512
  float* qkv = xl + 131072;        // 1024*1536
  float* ctx = qkv + 1572864;      // 1024*512
  float* tmp = ctx + 524288;       // 1024*512
  float* ff1 = tmp + 524288;       // 1024*2048
  unsigned short* ha_bf = (unsigned short*)(ff1 + 2097152);  // 1024*2048
  unsigned short* hl_bf = ha_bf + 2097152;                   // 256*2048
  unsigned short* Wb    = hl_bf + 524288;                    // 1024*2048

  // ---- audio path ----
  embed_audio_kernel<<<B * T, 256, 0, stream>>>(input_values, a_lin_w, a_lin_b,
                                                a_pos, xa, T);
  run_encoder(xa, B, T, 12, a_qkv_w, a_qkv_b, a_out_w, a_out_b, a_ff1_w,
              a_ff1_b, a_ff2_w, a_ff2_b, a_ln1_s, a_ln1_b, a_ln2_s, a_ln2_b,
              qkv, ctx, tmp, ff1, stream);

  // ---- label path ----
  embed_label_kernel<<<B * U, 256, 0, stream>>>(labels, l_word, l_pos, xl, U);
  run_encoder(xl, B, U, 4, l_qkv_w, l_qkv_b, l_out_w, l_out_b, l_ff1_w,
              l_ff1_b, l_ff2_w, l_ff2_b, l_ln1_s, l_ln1_b, l_ln2_s, l_ln2_b,
              qkv, ctx, tmp, ff1, stream);

  // ---- joint projections -> bf16 directly ----
  gemm_bf16_kernel<0, 1><<<dim3(KJOINT / 128, (B * T) / 128), 256, 0, stream>>>(
      xa, HD, joint_w, 1024, nullptr, ha_bf, KJOINT, B * T, KJOINT, HD);
  gemm_bf16_kernel<0, 1><<<dim3(KJOINT / 128, (B * U) / 128), 256, 0, stream>>>(
      xl, HD, joint_w + HD, 1024, joint_b, hl_bf, KJOINT, B * U, KJOINT, HD);

  // ---- out_w -> bf16 ----
  cvt_bf16_kernel<<<(VOUT * KJOINT) / 1024, 256, 0, stream>>>(out_w, Wb);

  // ---- joint MFMA + log-softmax ----
  joint_mfma_kernel<<<dim3(VOUT / JN, (B * T * U) / JM), 512, 0, stream>>>(
      ha_bf, hl_bf, Wb, out_b, (float*)d_out, T, U);
  logsoftmax_kernel<<<B * T * U, 256, 0, stream>>>((float*)d_out);
}